// Round 13
// baseline (931.959 us; speedup 1.0000x reference)
//
#include <hip/hip_runtime.h>

typedef unsigned short u16;
typedef unsigned int u32;
typedef __bf16 bf16x8 __attribute__((ext_vector_type(8)));
typedef float f32x4 __attribute__((ext_vector_type(4)));

#define NTOK 4097
#define MTOK 513
#define MPAD 544     // 34*16 (xln row padding)
#define KPAD 640     // K/V padded
#define NPAD_Q 4224  // 33*128
#define ROWS_X 16512 // 129*128 (gemm block-staged rows)
#define GRID_BLOCKS 1024

__device__ __forceinline__ u16 f2bf(float f) {  // RNE (outputs)
  u32 u = __builtin_bit_cast(u32, f);
  u = u + 0x7FFFu + ((u >> 16) & 1u);
  return (u16)(u >> 16);
}
__device__ __forceinline__ u16 f2bf_fast(float f) {  // round-half-up (internal P)
  u32 u = __builtin_bit_cast(u32, f);
  return (u16)((u + 0x8000u) >> 16);
}

// async global->LDS DMA, 16B per lane; LDS dest = wave-uniform base + lane*16
__device__ __forceinline__ void gld16(const u16* g, u16* l) {
  __builtin_amdgcn_global_load_lds((const __attribute__((address_space(1))) u32*)g,
                                   (__attribute__((address_space(3))) u32*)l, 16, 0, 0);
}

// grid barrier: device-scope atomics; __threadfence -> buffer_wbl2/inv (cross-XCD per G16)
__device__ __forceinline__ void gbar(u32* c) {
  __threadfence();
  __syncthreads();
  if (threadIdx.x == 0) {
    atomicAdd(c, 1u);
    while (atomicAdd(c, 0u) < (u32)GRID_BLOCKS) __builtin_amdgcn_s_sleep(8);
  }
  __syncthreads();
  __threadfence();
}

#define NX   6292992  // 4*4097*384
#define NQW  147456
#define NKVW 294912
#define NPW  147456
#define GX   (NX / 8)
#define GQW  (NQW / 8)
#define GKVW (NKVW / 8)
#define GPW  (NPW / 8)
#define GTOT (GX + GQW + GKVW + GPW)

__device__ __forceinline__ float srln_val(const float* __restrict__ x, const float* __restrict__ srw,
                                          const float* __restrict__ srb, int b, int m, int c) {
  if (m == 0) return x[(b * NTOK) * 384 + c];
  int mo = m - 1;
  int oz = mo >> 6, oy = (mo >> 3) & 7, ox = mo & 7;
  float acc = srb[c];
#pragma unroll
  for (int dz = 0; dz < 2; dz++)
#pragma unroll
    for (int dy = 0; dy < 2; dy++)
#pragma unroll
      for (int dx = 0; dx < 2; dx++) {
        int tok = 1 + ((2 * oz + dz) * 256 + (2 * oy + dy) * 16 + (2 * ox + dx));
        acc += x[(b * NTOK + tok) * 384 + c] * srw[c * 8 + dz * 4 + dy * 2 + dx];
      }
  return acc;
}

// GEMM core, BK=32 variant (same ascending k-windows as R10 -> bitwise-identical sums).
// 128x128 tile, 4 waves own 64x64 quadrants. A/W DMA-staged dbuf, XOR swizzle ch^(row&3).
// LDS: aL/bL 2*4096 u16 each = 32 KB total. 16 MFMA + 4 DMA per barrier.
__device__ __forceinline__ void gemm_core32(u16* aL, u16* bL,
                                            const u16* __restrict__ A, const u16* __restrict__ W,
                                            int mode, size_t rbase, int c0,
                                            u16* __restrict__ o1, u16* __restrict__ o2,
                                            float* __restrict__ of, const float* __restrict__ bias) {
  int tid = threadIdx.x, w = tid >> 6, lane = tid & 63, q4 = lane >> 4, c16 = lane & 15;
  int wr = w >> 1, wc = w & 1;
  int x3 = c16 & 3;

  auto stageAB = [&](int kc, int buf) {
#pragma unroll
    for (int i = 0; i < 2; i++) {
      int s = (w * 2 + i) * 64 + lane;
      int row = s >> 2, chp = s & 3;
      int ch = chp ^ (row & 3);
      gld16(A + (rbase + row) * 384 + kc * 32 + ch * 8, &aL[buf * 4096 + (w * 2 + i) * 512]);
    }
#pragma unroll
    for (int i = 0; i < 2; i++) {
      int s = (w * 2 + i) * 64 + lane;
      int row = s >> 2, chp = s & 3;
      int ch = chp ^ (row & 3);
      gld16(W + (size_t)(c0 + row) * 384 + kc * 32 + ch * 8, &bL[buf * 4096 + (w * 2 + i) * 512]);
    }
  };
  stageAB(0, 0);
  __syncthreads();

  f32x4 acc[4][4];
#pragma unroll
  for (int mt = 0; mt < 4; mt++)
#pragma unroll
    for (int nt = 0; nt < 4; nt++) acc[mt][nt] = (f32x4){0, 0, 0, 0};

  for (int kc = 0; kc < 12; kc++) {
    int cb = kc & 1, nb = cb ^ 1;
    if (kc < 11) stageAB(kc + 1, nb);  // async; drains at this iter's end barrier
    bf16x8 af[4], bf[4];
#pragma unroll
    for (int mt = 0; mt < 4; mt++)
      af[mt] = *(const bf16x8*)(&aL[cb * 4096 + (wr * 64 + mt * 16 + c16) * 32 + (q4 ^ x3) * 8]);
#pragma unroll
    for (int nt = 0; nt < 4; nt++)
      bf[nt] = *(const bf16x8*)(&bL[cb * 4096 + (wc * 64 + nt * 16 + c16) * 32 + (q4 ^ x3) * 8]);
#pragma unroll
    for (int mt = 0; mt < 4; mt++)
#pragma unroll
      for (int nt = 0; nt < 4; nt++)
        acc[mt][nt] = __builtin_amdgcn_mfma_f32_16x16x32_bf16(af[mt], bf[nt], acc[mt][nt], 0, 0, 0);
    __syncthreads();
  }

#pragma unroll
  for (int mt = 0; mt < 4; mt++)
#pragma unroll
    for (int nt = 0; nt < 4; nt++) {
      int col = c0 + wc * 64 + nt * 16 + c16;
#pragma unroll
      for (int r = 0; r < 4; r++) {
        int R = (int)rbase + wr * 64 + mt * 16 + q4 * 4 + r;
        float val = acc[mt][nt][r];
        if (mode == 0) {
          int b = R / NTOK;
          if (b >= 4) continue;
          int n = R - b * NTOK;
          int h = col / 48, d = col - h * 48;
          o1[((size_t)(b * 8 + h) * NPAD_Q + n) * 64 + d] = f2bf(val * 0.14433756729740643f);
        } else if (mode == 1) {
          int b = R / MPAD;
          int m = R - b * MPAD;
          if (col < 384) {
            int h = col / 48, d = col - h * 48;
            o1[((size_t)(b * 8 + h) * KPAD + m) * 64 + d] = f2bf(val);
          } else {
            int c2 = col - 384;
            int h = c2 / 48, d = c2 - h * 48;
            o2[((size_t)(b * 8 + h) * 48 + d) * KPAD + m] = f2bf(val);
          }
        } else {
          if (R < 4 * NTOK) of[(size_t)R * 384 + col] = val + bias[col];
        }
      }
    }
}

// ---------------- persistent mega-kernel: pre -> qkv -> attn -> out ----------------
extern "C" __global__ void __launch_bounds__(256, 4)
mega(const float* __restrict__ x, const float* __restrict__ qw, const float* __restrict__ kvw,
     const float* __restrict__ pw, const float* __restrict__ srw, const float* __restrict__ srb,
     const float* __restrict__ lng, const float* __restrict__ lnb, const float* __restrict__ pb,
     float* __restrict__ out,
     u16* __restrict__ xb, u16* __restrict__ qwb, u16* __restrict__ kvwb, u16* __restrict__ pwb,
     u16* __restrict__ qb, u16* __restrict__ xlnb, u16* __restrict__ kb, u16* __restrict__ vtb,
     u32* __restrict__ bar) {
  __shared__ __align__(16) unsigned char smem_raw[38400];  // union of all phases
  u16* smem = (u16*)smem_raw;
  int tid = threadIdx.x;

  // barrier init (block 0) behind atomic flag; 0xAA poison != magic
  if (blockIdx.x == 0 && tid == 0) {
    atomicExch(&bar[8], 0u);
    atomicExch(&bar[16], 0u);
    atomicExch(&bar[24], 0u);
    __threadfence();
    atomicExch(&bar[0], 0x0C0FFEE1u);
  }

  // ---- P0: sr_ln (256-thread variant: channel c and c+256) + vectorized casts ----
  {
    float* red = (float*)smem;
    int c = tid, w = tid >> 6, lane = tid & 63;
    for (int u = blockIdx.x; u < 4 * MTOK; u += GRID_BLOCKS) {
      int b = u / MTOK, m = u - b * MTOK;
      float v0 = srln_val(x, srw, srb, b, m, c);
      float v1 = (c < 128) ? srln_val(x, srw, srb, b, m, c + 256) : 0.f;
      float s1 = v0 + v1, s2 = v0 * v0 + v1 * v1;
#pragma unroll
      for (int msk = 32; msk >= 1; msk >>= 1) {
        s1 += __shfl_xor(s1, msk);
        s2 += __shfl_xor(s2, msk);
      }
      __syncthreads();
      if (lane == 0) { red[w] = s1; red[4 + w] = s2; }
      __syncthreads();
      float S1 = red[0] + red[1] + red[2] + red[3];
      float S2 = red[4] + red[5] + red[6] + red[7];
      float mu = S1 * (1.0f / 384.0f);
      float var = S2 * (1.0f / 384.0f) - mu * mu;
      float rs = rsqrtf(var + 1e-5f);
      xlnb[((size_t)(b * MPAD + m)) * 384 + c] = f2bf((v0 - mu) * rs * lng[c] + lnb[c]);
      if (c < 128)
        xlnb[((size_t)(b * MPAD + m)) * 384 + c + 256] = f2bf((v1 - mu) * rs * lng[c + 256] + lnb[c + 256]);
    }
    int gid = blockIdx.x * 256 + tid;
    for (int g = gid; g < GTOT; g += GRID_BLOCKS * 256) {
      const float* s;
      u16* d;
      int off;
      if (g < GX) { s = x; d = xb; off = g * 8; }
      else if (g < GX + GQW) { s = qw; d = qwb; off = (g - GX) * 8; }
      else if (g < GX + GQW + GKVW) { s = kvw; d = kvwb; off = (g - GX - GQW) * 8; }
      else { s = pw; d = pwb; off = (g - GX - GQW - GKVW) * 8; }
      float4 v0 = *(const float4*)(s + off);
      float4 v1 = *(const float4*)(s + off + 4);
      uint4 o;
      u16* p = (u16*)&o;
      p[0] = f2bf(v0.x); p[1] = f2bf(v0.y); p[2] = f2bf(v0.z); p[3] = f2bf(v0.w);
      p[4] = f2bf(v1.x); p[5] = f2bf(v1.y); p[6] = f2bf(v1.z); p[7] = f2bf(v1.w);
      *(uint4*)(d + off) = o;
    }
  }
  if (tid == 0) {
    while (atomicAdd(&bar[0], 0u) != 0x0C0FFEE1u) __builtin_amdgcn_s_sleep(8);
  }
  __syncthreads();
  gbar(&bar[8]);

  // ---- P1: q-proj (387 tiles) + kv-proj (102 tiles) ----
  {
    u16* aL = smem;
    u16* bL = smem + 8192;
    for (int t = blockIdx.x; t < 489; t += GRID_BLOCKS) {
      if (t < 387)
        gemm_core32(aL, bL, xb, qwb, 0, (size_t)(t % 129) * 128, (t / 129) * 128,
                    qb, nullptr, nullptr, nullptr);
      else {
        int i = t - 387;
        gemm_core32(aL, bL, xlnb, kvwb, 1, (size_t)(i % 17) * 128, (i / 17) * 128,
                    kb, vtb, nullptr, nullptr);
      }
    }
  }
  gbar(&bar[16]);

  // ---- P2: attention (R11-proven body; 1056 units, bh = u&31 for XCD locality) ----
  {
    u16* kl = smem;                 // 2*64*64
    u16* vl = smem + 8192;          // 2*48*64
    u16* pl = smem + 8192 + 6144;   // 4*16*76
    int w = tid >> 6, lane = tid & 63, q4 = lane >> 4, c16 = lane & 15;
    int r7 = c16 & 7;
    for (int u = blockIdx.x; u < 1056; u += GRID_BLOCKS) {
      int bh = u & 31;
      int n0 = (u >> 5) * 128 + w * 32;

      const uint4* qp = (const uint4*)(qb + ((size_t)bh * NPAD_Q + n0 + c16) * 64);
      bf16x8 aq[2][2];
#pragma unroll
      for (int rg = 0; rg < 2; rg++) {
        aq[rg][0] = __builtin_bit_cast(bf16x8, qp[rg * 128 + q4]);
        aq[rg][1] = __builtin_bit_cast(bf16x8, qp[rg * 128 + 4 + q4]);
      }
      const u16* kbase = kb + (size_t)bh * KPAD * 64;
      const u16* vbase = vtb + (size_t)bh * 48 * KPAD;

      auto stage = [&](int cn, int buf) {
#pragma unroll
        for (int i = 0; i < 2; i++) {
          int s = (w * 2 + i) * 64 + lane;
          int row = s >> 3, chp = s & 7;
          int ch = chp ^ (row & 7);
          gld16(kbase + (size_t)(cn * 64 + row) * 64 + ch * 8, &kl[buf * 4096 + (w * 2 + i) * 512]);
        }
#pragma unroll
        for (int i = 0; i < 2; i++) {
          int blk = w * 2 + i;
          if (blk < 6) {
            int s = blk * 64 + lane;
            int row = s >> 3, chp = s & 7;
            int ch = chp ^ (row & 7);
            gld16(vbase + (size_t)row * KPAD + cn * 64 + ch * 8, &vl[buf * 3072 + blk * 512]);
          }
        }
      };

      stage(0, 0);
      __syncthreads();

      f32x4 o[2][3];
      float lsum[2][4];
#pragma unroll
      for (int rg = 0; rg < 2; rg++) {
#pragma unroll
        for (int nt = 0; nt < 3; nt++) o[rg][nt] = (f32x4){0, 0, 0, 0};
#pragma unroll
        for (int r = 0; r < 4; r++) lsum[rg][r] = 0.f;
      }

      for (int c = 0; c < 8; c++) {
        int cb = c & 1, nb = cb ^ 1;
        stage(c + 1, nb);  // c=7 stages tail (keys 512..575) into buffer 0

        f32x4 s[2][4];
#pragma unroll
        for (int rg = 0; rg < 2; rg++)
#pragma unroll
          for (int t = 0; t < 4; t++) s[rg][t] = (f32x4){0, 0, 0, 0};
#pragma unroll
        for (int t = 0; t < 4; t++) {
          const u16* krow = &kl[cb * 4096 + (t * 16 + c16) * 64];
          bf16x8 k0 = *(const bf16x8*)(krow + (q4 ^ r7) * 8);
          bf16x8 k1 = *(const bf16x8*)(krow + ((q4 ^ r7) ^ 4) * 8);
#pragma unroll
          for (int rg = 0; rg < 2; rg++) {
            s[rg][t] = __builtin_amdgcn_mfma_f32_16x16x32_bf16(aq[rg][0], k0, s[rg][t], 0, 0, 0);
            s[rg][t] = __builtin_amdgcn_mfma_f32_16x16x32_bf16(aq[rg][1], k1, s[rg][t], 0, 0, 0);
          }
        }
#pragma unroll
        for (int rg = 0; rg < 2; rg++)
#pragma unroll
          for (int t = 0; t < 4; t++)
#pragma unroll
            for (int r = 0; r < 4; r++) {
              float e = __expf(s[rg][t][r]);
              s[rg][t][r] = e;
              lsum[rg][r] += e;
            }
        bf16x8 afrag[2][2];
#pragma unroll
        for (int rg = 0; rg < 2; rg++) {
#pragma unroll
          for (int t = 0; t < 4; t++)
#pragma unroll
            for (int r = 0; r < 4; r++)
              pl[w * 1216 + (q4 * 4 + r) * 76 + t * 16 + c16] = f2bf_fast(s[rg][t][r]);
#pragma unroll
          for (int kl2 = 0; kl2 < 2; kl2++)
            afrag[rg][kl2] = *(const bf16x8*)(&pl[w * 1216 + c16 * 76 + kl2 * 32 + q4 * 8]);
        }
#pragma unroll
        for (int kl2 = 0; kl2 < 2; kl2++)
#pragma unroll
          for (int nt = 0; nt < 3; nt++) {
            const u16* vrow = &vl[cb * 3072 + (nt * 16 + c16) * 64];
            bf16x8 bv = *(const bf16x8*)(vrow + ((kl2 * 4 + q4) ^ r7) * 8);
#pragma unroll
            for (int rg = 0; rg < 2; rg++)
              o[rg][nt] = __builtin_amdgcn_mfma_f32_16x16x32_bf16(afrag[rg][kl2], bv, o[rg][nt], 0, 0, 0);
          }
        __syncthreads();
      }

      // tail: keys 512..527 in buffer 0; only key 512 (c16==0) valid
      {
        f32x4 s4[2] = {{0, 0, 0, 0}, {0, 0, 0, 0}};
        const u16* krow = &kl[c16 * 64];
        bf16x8 k0 = *(const bf16x8*)(krow + (q4 ^ r7) * 8);
        bf16x8 k1 = *(const bf16x8*)(krow + ((q4 ^ r7) ^ 4) * 8);
#pragma unroll
        for (int rg = 0; rg < 2; rg++) {
          s4[rg] = __builtin_amdgcn_mfma_f32_16x16x32_bf16(aq[rg][0], k0, s4[rg], 0, 0, 0);
          s4[rg] = __builtin_amdgcn_mfma_f32_16x16x32_bf16(aq[rg][1], k1, s4[rg], 0, 0, 0);
        }
        bf16x8 afrag[2];
#pragma unroll
        for (int rg = 0; rg < 2; rg++) {
#pragma unroll
          for (int r = 0; r < 4; r++) {
            float e = (c16 == 0) ? __expf(s4[rg][r]) : 0.f;
            lsum[rg][r] += e;
            pl[w * 1216 + (q4 * 4 + r) * 76 + c16] = f2bf_fast(e);
            pl[w * 1216 + (q4 * 4 + r) * 76 + 16 + c16] = 0;
          }
          afrag[rg] = *(const bf16x8*)(&pl[w * 1216 + c16 * 76 + q4 * 8]);
        }
#pragma unroll
        for (int nt = 0; nt < 3; nt++) {
          const u16* vrow = &vl[(nt * 16 + c16) * 64];
          bf16x8 bv = *(const bf16x8*)(vrow + (q4 ^ r7) * 8);
#pragma unroll
          for (int rg = 0; rg < 2; rg++)
            o[rg][nt] = __builtin_amdgcn_mfma_f32_16x16x32_bf16(afrag[rg], bv, o[rg][nt], 0, 0, 0);
        }
      }

      int b = bh >> 3, h = bh & 7;
#pragma unroll
      for (int rg = 0; rg < 2; rg++) {
        float inv[4];
#pragma unroll
        for (int r = 0; r < 4; r++) {
          float l = lsum[rg][r];
          l += __shfl_xor(l, 1);
          l += __shfl_xor(l, 2);
          l += __shfl_xor(l, 4);
          l += __shfl_xor(l, 8);
          inv[r] = 1.0f / l;
        }
#pragma unroll
        for (int nt = 0; nt < 3; nt++)
#pragma unroll
          for (int r = 0; r < 4; r++) {
            int n = n0 + rg * 16 + q4 * 4 + r;
            if (n < NTOK)
              xb[((size_t)(b * NTOK + n)) * 384 + h * 48 + nt * 16 + c16] = f2bf(o[rg][nt][r] * inv[r]);
          }
      }
      __syncthreads();  // protect LDS before next unit's stage(0,0)
    }
  }
  gbar(&bar[24]);

  // ---- P3: out-proj (387 tiles); A = attn output aliased in xb ----
  {
    u16* aL = smem;
    u16* bL = smem + 8192;
    for (int t = blockIdx.x; t < 387; t += GRID_BLOCKS)
      gemm_core32(aL, bL, xb, pwb, 2, (size_t)(t % 129) * 128, (t / 129) * 128,
                  nullptr, nullptr, out, pb);
  }
}

extern "C" void kernel_launch(void* const* d_in, const int* in_sizes, int n_in,
                              void* d_out, int out_size, void* d_ws, size_t ws_size,
                              hipStream_t stream) {
  const float* x = (const float*)d_in[0];
  const float* q_w = (const float*)d_in[1];
  const float* kv_w = (const float*)d_in[2];
  const float* proj_w = (const float*)d_in[3];
  const float* proj_b = (const float*)d_in[4];
  const float* sr_w = (const float*)d_in[5];
  const float* sr_b = (const float*)d_in[6];
  const float* ln_g = (const float*)d_in[7];
  const float* ln_b = (const float*)d_in[8];
  float* out = (float*)d_out;

  u16* ws = (u16*)d_ws;
  u16* x_b = ws;                          // 16512*384       = 6,340,608
  u16* qw_b = x_b + (size_t)ROWS_X * 384; // 147,456
  u16* kvw_b = qw_b + 147456;             // 294,912
  u16* pw_b = kvw_b + 294912;             // 147,456
  u16* q_b = pw_b + 147456;               // 32*4224*64      = 8,650,752
  u16* xln_b = q_b + (size_t)32 * NPAD_Q * 64;  // 4*544*384 = 835,584
  u16* k_b = xln_b + (size_t)4 * MPAD * 384;    // 32*640*64 = 1,310,720
  u16* vt_b = k_b + (size_t)32 * KPAD * 64;     // 32*48*640 = 983,040
  u32* bar = (u32*)(vt_b + (size_t)32 * 48 * KPAD);  // 128 u32 barrier region

  mega<<<GRID_BLOCKS, 256, 0, stream>>>(x, q_w, kv_w, proj_w, sr_w, sr_b, ln_g, ln_b, proj_b,
                                        out, x_b, qw_b, kvw_b, pw_b, q_b, xln_b, k_b, vt_b, bar);
}

// Round 14
// 181.411 us; speedup vs baseline: 5.1373x; 5.1373x over previous
//
#include <hip/hip_runtime.h>

typedef unsigned short u16;
typedef unsigned int u32;
typedef __bf16 bf16x8 __attribute__((ext_vector_type(8)));
typedef float f32x4 __attribute__((ext_vector_type(4)));

#define NTOK 4097
#define MTOK 513
#define MPAD 544     // 34*16 (xln row padding)
#define KPAD 640     // K/V padded
#define NPAD_Q 4224  // 33*128
#define ROWS_X 16512 // 129*128 (gemm block-staged rows)

__device__ __forceinline__ u16 f2bf(float f) {  // RNE (outputs)
  u32 u = __builtin_bit_cast(u32, f);
  u = u + 0x7FFFu + ((u >> 16) & 1u);
  return (u16)(u >> 16);
}
__device__ __forceinline__ u16 f2bf_fast(float f) {  // round-half-up (internal P)
  u32 u = __builtin_bit_cast(u32, f);
  return (u16)((u + 0x8000u) >> 16);
}

// async global->LDS DMA, 16B per lane; LDS dest = wave-uniform base + lane*16
__device__ __forceinline__ void gld16(const u16* g, u16* l) {
  __builtin_amdgcn_global_load_lds((const __attribute__((address_space(1))) u32*)g,
                                   (__attribute__((address_space(3))) u32*)l, 16, 0, 0);
}

// ---------------- fused pre-pass: sr_ln (blocks 0..2051) + vectorized casts ----------------
#define NX   6292992  // 4*4097*384
#define NQW  147456
#define NKVW 294912
#define NPW  147456
#define GX   (NX / 8)
#define GQW  (NQW / 8)
#define GKVW (NKVW / 8)
#define GPW  (NPW / 8)
#define GTOT (GX + GQW + GKVW + GPW)  // 860,352 8-elem groups
#define SRLN_BLOCKS (4 * MTOK)        // 2052

__global__ void pre_kernel(const float* __restrict__ x, const float* __restrict__ qw,
                           const float* __restrict__ kvw, const float* __restrict__ pw,
                           const float* __restrict__ srw, const float* __restrict__ srb,
                           const float* __restrict__ lng, const float* __restrict__ lnb,
                           u16* __restrict__ xb, u16* __restrict__ qwb,
                           u16* __restrict__ kvwb, u16* __restrict__ pwb,
                           u16* __restrict__ xln) {
  if (blockIdx.x < SRLN_BLOCKS) {
    int c = threadIdx.x;  // 0..383
    int bm = blockIdx.x;
    int b = bm / MTOK, m = bm - b * MTOK;
    float v;
    if (m == 0) {
      v = x[(b * NTOK) * 384 + c];
    } else {
      int mo = m - 1;
      int oz = mo >> 6, oy = (mo >> 3) & 7, ox = mo & 7;
      float acc = srb[c];
#pragma unroll
      for (int dz = 0; dz < 2; dz++)
#pragma unroll
        for (int dy = 0; dy < 2; dy++)
#pragma unroll
          for (int dx = 0; dx < 2; dx++) {
            int tok = 1 + ((2 * oz + dz) * 256 + (2 * oy + dy) * 16 + (2 * ox + dx));
            acc += x[(b * NTOK + tok) * 384 + c] * srw[c * 8 + dz * 4 + dy * 2 + dx];
          }
      v = acc;
    }
    float s1 = v, s2 = v * v;
#pragma unroll
    for (int msk = 32; msk >= 1; msk >>= 1) {
      s1 += __shfl_xor(s1, msk);
      s2 += __shfl_xor(s2, msk);
    }
    __shared__ float r1[6], r2[6];
    int w = threadIdx.x >> 6, lane = threadIdx.x & 63;
    if (lane == 0) { r1[w] = s1; r2[w] = s2; }
    __syncthreads();
    float S1 = 0.f, S2 = 0.f;
#pragma unroll
    for (int i = 0; i < 6; i++) { S1 += r1[i]; S2 += r2[i]; }
    float mu = S1 * (1.0f / 384.0f);
    float var = S2 * (1.0f / 384.0f) - mu * mu;
    float y = (v - mu) * rsqrtf(var + 1e-5f) * lng[c] + lnb[c];
    xln[(b * MPAD + m) * 384 + c] = f2bf(y);
  } else {
    int idx = (blockIdx.x - SRLN_BLOCKS) * blockDim.x + threadIdx.x;
    int stride = (gridDim.x - SRLN_BLOCKS) * blockDim.x;
    for (int g = idx; g < GTOT; g += stride) {
      const float* s;
      u16* d;
      int off;
      if (g < GX) { s = x; d = xb; off = g * 8; }
      else if (g < GX + GQW) { s = qw; d = qwb; off = (g - GX) * 8; }
      else if (g < GX + GQW + GKVW) { s = kvw; d = kvwb; off = (g - GX - GQW) * 8; }
      else { s = pw; d = pwb; off = (g - GX - GQW - GKVW) * 8; }
      float4 v0 = *(const float4*)(s + off);
      float4 v1 = *(const float4*)(s + off + 4);
      uint4 o;
      u16* p = (u16*)&o;
      p[0] = f2bf(v0.x); p[1] = f2bf(v0.y); p[2] = f2bf(v0.z); p[3] = f2bf(v0.w);
      p[4] = f2bf(v1.x); p[5] = f2bf(v1.y); p[6] = f2bf(v1.z); p[7] = f2bf(v1.w);
      *(uint4*)(d + off) = o;
    }
  }
}

// ---------------- GEMM core (R12-proven, BK=64) ----------------
__device__ __forceinline__ void gemm_core(u16* aLds, u16* bLds,
                                          const u16* __restrict__ A, const u16* __restrict__ W,
                                          int mode, size_t rbase, int c0,
                                          u16* __restrict__ o1, u16* __restrict__ o2,
                                          float* __restrict__ of, const float* __restrict__ bias) {
  int tid = threadIdx.x, w = tid >> 6, lane = tid & 63, q4 = lane >> 4, c16 = lane & 15;
  int wr = w >> 1, wc = w & 1;
  int x7 = c16 & 7;

  auto stageAB = [&](int kc, int buf) {
#pragma unroll
    for (int i = 0; i < 4; i++) {
      int s = (w * 4 + i) * 64 + lane;
      int row = s >> 3, chp = s & 7;
      int ch = chp ^ (row & 7);
      gld16(A + (rbase + row) * 384 + kc * 64 + ch * 8, &aLds[buf * 8192 + (w * 4 + i) * 512]);
    }
#pragma unroll
    for (int i = 0; i < 4; i++) {
      int s = (w * 4 + i) * 64 + lane;
      int row = s >> 3, chp = s & 7;
      int ch = chp ^ (row & 7);
      gld16(W + (size_t)(c0 + row) * 384 + kc * 64 + ch * 8, &bLds[buf * 8192 + (w * 4 + i) * 512]);
    }
  };
  stageAB(0, 0);
  __syncthreads();

  f32x4 acc[4][4];
#pragma unroll
  for (int mt = 0; mt < 4; mt++)
#pragma unroll
    for (int nt = 0; nt < 4; nt++) acc[mt][nt] = (f32x4){0, 0, 0, 0};

  for (int c = 0; c < 6; c++) {
    int cb = c & 1, nb = cb ^ 1;
    if (c < 5) stageAB(c + 1, nb);  // async; drains at this iter's end barrier
#pragma unroll
    for (int ks = 0; ks < 2; ks++) {
      bf16x8 af[4], bf[4];
#pragma unroll
      for (int mt = 0; mt < 4; mt++)
        af[mt] = *(const bf16x8*)(&aLds[cb * 8192 + (wr * 64 + mt * 16 + c16) * 64 + ((ks * 4 + q4) ^ x7) * 8]);
#pragma unroll
      for (int nt = 0; nt < 4; nt++)
        bf[nt] = *(const bf16x8*)(&bLds[cb * 8192 + (wc * 64 + nt * 16 + c16) * 64 + ((ks * 4 + q4) ^ x7) * 8]);
#pragma unroll
      for (int mt = 0; mt < 4; mt++)
#pragma unroll
        for (int nt = 0; nt < 4; nt++)
          acc[mt][nt] = __builtin_amdgcn_mfma_f32_16x16x32_bf16(af[mt], bf[nt], acc[mt][nt], 0, 0, 0);
    }
    __syncthreads();
  }

#pragma unroll
  for (int mt = 0; mt < 4; mt++)
#pragma unroll
    for (int nt = 0; nt < 4; nt++) {
      int col = c0 + wc * 64 + nt * 16 + c16;
#pragma unroll
      for (int r = 0; r < 4; r++) {
        int R = (int)rbase + wr * 64 + mt * 16 + q4 * 4 + r;
        float val = acc[mt][nt][r];
        if (mode == 0) {
          int b = R / NTOK;
          if (b >= 4) continue;
          int n = R - b * NTOK;
          int h = col / 48, d = col - h * 48;
          o1[((size_t)(b * 8 + h) * NPAD_Q + n) * 64 + d] = f2bf(val * 0.14433756729740643f);
        } else if (mode == 1) {
          int b = R / MPAD;
          int m = R - b * MPAD;
          if (col < 384) {
            int h = col / 48, d = col - h * 48;
            o1[((size_t)(b * 8 + h) * KPAD + m) * 64 + d] = f2bf(val);
          } else {
            int c2 = col - 384;
            int h = c2 / 48, d = c2 - h * 48;
            o2[((size_t)(b * 8 + h) * 48 + d) * KPAD + m] = f2bf(val);
          }
        } else {
          if (R < 4 * NTOK) of[(size_t)R * 384 + col] = val + bias[col];
        }
      }
    }
}

// fused q-proj (blocks 0..386) + kv-proj (blocks 387..488)
__global__ __launch_bounds__(256) void gemm_qkv(const u16* __restrict__ xb, const u16* __restrict__ qwb,
                                                const u16* __restrict__ xlnb, const u16* __restrict__ kvwb,
                                                u16* __restrict__ qb, u16* __restrict__ kb2,
                                                u16* __restrict__ vtb) {
  __shared__ __align__(16) u16 aLds[2 * 128 * 64];
  __shared__ __align__(16) u16 bLds[2 * 128 * 64];
  int bx = blockIdx.x;
  if (bx < 387) {
    gemm_core(aLds, bLds, xb, qwb, 0, (size_t)(bx % 129) * 128, (bx / 129) * 128,
              qb, nullptr, nullptr, nullptr);
  } else {
    int i = bx - 387;
    gemm_core(aLds, bLds, xlnb, kvwb, 1, (size_t)(i % 17) * 128, (i / 17) * 128,
              kb2, vtb, nullptr, nullptr);
  }
}

// out-proj (mode 2)
__global__ __launch_bounds__(256) void gemm_out(const u16* __restrict__ A, const u16* __restrict__ W,
                                                float* __restrict__ of, const float* __restrict__ bias) {
  __shared__ __align__(16) u16 aLds[2 * 128 * 64];
  __shared__ __align__(16) u16 bLds[2 * 128 * 64];
  gemm_core(aLds, bLds, A, W, 2, (size_t)blockIdx.x * 128, blockIdx.y * 128,
            nullptr, nullptr, of, bias);
}

// ---------------- Attention: persistent 1024 blocks over 1056 units ----------------
// Body = R13 P2 (correctness-verified inside mega). Removes the 32-block straggler tail
// of the 1056-block grid (1024 resident slots at 4 blocks/CU).
__global__ __launch_bounds__(256, 4) void attn_kernel(const u16* __restrict__ qb,
                                                      const u16* __restrict__ kb,
                                                      const u16* __restrict__ vt,
                                                      u16* __restrict__ outb) {
  __shared__ __align__(16) u16 klds[2][64][64];   // 16,384 B (unpadded: DMA dest)
  __shared__ __align__(16) u16 vlds[2][48][64];   // 12,288 B
  __shared__ __align__(16) u16 plds[4][16][76];   //  9,728 B (wave-private P scratch)
  int tid = threadIdx.x, w = tid >> 6, lane = tid & 63, q4 = lane >> 4, c16 = lane & 15;
  int r7 = c16 & 7;

  for (int u = blockIdx.x; u < 1056; u += 1024) {
    int bh = u & 31;                 // XCD locality: consecutive blocks span all bh
    int n0 = (u >> 5) * 128 + w * 32;

    const uint4* qp = (const uint4*)(qb + ((size_t)bh * NPAD_Q + n0 + c16) * 64);
    bf16x8 aq[2][2];
#pragma unroll
    for (int rg = 0; rg < 2; rg++) {
      aq[rg][0] = __builtin_bit_cast(bf16x8, qp[rg * 128 + q4]);
      aq[rg][1] = __builtin_bit_cast(bf16x8, qp[rg * 128 + 4 + q4]);
    }
    const u16* kbase = kb + (size_t)bh * KPAD * 64;
    const u16* vbase = vt + (size_t)bh * 48 * KPAD;

    auto stage = [&](int cn, int buf) {
#pragma unroll
      for (int i = 0; i < 2; i++) {
        int s = (w * 2 + i) * 64 + lane;
        int row = s >> 3, chp = s & 7;
        int ch = chp ^ (row & 7);
        gld16(kbase + (size_t)(cn * 64 + row) * 64 + ch * 8, &klds[buf][(w * 2 + i) * 8][0]);
      }
#pragma unroll
      for (int i = 0; i < 2; i++) {
        int blk = w * 2 + i;
        if (blk < 6) {
          int s = blk * 64 + lane;
          int row = s >> 3, chp = s & 7;
          int ch = chp ^ (row & 7);
          gld16(vbase + (size_t)row * KPAD + cn * 64 + ch * 8, &vlds[buf][blk * 8][0]);
        }
      }
    };

    stage(0, 0);
    __syncthreads();

    f32x4 o[2][3];
    float lsum[2][4];
#pragma unroll
    for (int rg = 0; rg < 2; rg++) {
#pragma unroll
      for (int nt = 0; nt < 3; nt++) o[rg][nt] = (f32x4){0, 0, 0, 0};
#pragma unroll
      for (int r = 0; r < 4; r++) lsum[rg][r] = 0.f;
    }

    for (int c = 0; c < 8; c++) {
      int cb = c & 1, nb = cb ^ 1;
      stage(c + 1, nb);  // c=7 stages tail (keys 512..575) into buffer 0

      f32x4 s[2][4];
#pragma unroll
      for (int rg = 0; rg < 2; rg++)
#pragma unroll
        for (int t = 0; t < 4; t++) s[rg][t] = (f32x4){0, 0, 0, 0};
#pragma unroll
      for (int t = 0; t < 4; t++) {
        const u16* krow = &klds[cb][t * 16 + c16][0];
        bf16x8 k0 = *(const bf16x8*)(krow + (q4 ^ r7) * 8);
        bf16x8 k1 = *(const bf16x8*)(krow + ((q4 ^ r7) ^ 4) * 8);
#pragma unroll
        for (int rg = 0; rg < 2; rg++) {
          s[rg][t] = __builtin_amdgcn_mfma_f32_16x16x32_bf16(aq[rg][0], k0, s[rg][t], 0, 0, 0);
          s[rg][t] = __builtin_amdgcn_mfma_f32_16x16x32_bf16(aq[rg][1], k1, s[rg][t], 0, 0, 0);
        }
      }
#pragma unroll
      for (int rg = 0; rg < 2; rg++)
#pragma unroll
        for (int t = 0; t < 4; t++)
#pragma unroll
          for (int r = 0; r < 4; r++) {
            float e = __expf(s[rg][t][r]);
            s[rg][t][r] = e;
            lsum[rg][r] += e;
          }
      bf16x8 afrag[2][2];
#pragma unroll
      for (int rg = 0; rg < 2; rg++) {
#pragma unroll
        for (int t = 0; t < 4; t++)
#pragma unroll
          for (int r = 0; r < 4; r++) plds[w][q4 * 4 + r][t * 16 + c16] = f2bf_fast(s[rg][t][r]);
#pragma unroll
        for (int kl = 0; kl < 2; kl++)
          afrag[rg][kl] = *(const bf16x8*)(&plds[w][c16][kl * 32 + q4 * 8]);
      }
#pragma unroll
      for (int kl = 0; kl < 2; kl++)
#pragma unroll
        for (int nt = 0; nt < 3; nt++) {
          const u16* vrow = &vlds[cb][nt * 16 + c16][0];
          bf16x8 bv = *(const bf16x8*)(vrow + ((kl * 4 + q4) ^ r7) * 8);
#pragma unroll
          for (int rg = 0; rg < 2; rg++)
            o[rg][nt] = __builtin_amdgcn_mfma_f32_16x16x32_bf16(afrag[rg][kl], bv, o[rg][nt], 0, 0, 0);
        }
      __syncthreads();
    }

    // tail: keys 512..527 in buffer 0; only key 512 (c16==0) valid
    {
      f32x4 s4[2] = {{0, 0, 0, 0}, {0, 0, 0, 0}};
      const u16* krow = &klds[0][c16][0];
      bf16x8 k0 = *(const bf16x8*)(krow + (q4 ^ r7) * 8);
      bf16x8 k1 = *(const bf16x8*)(krow + ((q4 ^ r7) ^ 4) * 8);
#pragma unroll
      for (int rg = 0; rg < 2; rg++) {
        s4[rg] = __builtin_amdgcn_mfma_f32_16x16x32_bf16(aq[rg][0], k0, s4[rg], 0, 0, 0);
        s4[rg] = __builtin_amdgcn_mfma_f32_16x16x32_bf16(aq[rg][1], k1, s4[rg], 0, 0, 0);
      }
      bf16x8 afrag[2];
#pragma unroll
      for (int rg = 0; rg < 2; rg++) {
#pragma unroll
        for (int r = 0; r < 4; r++) {
          float e = (c16 == 0) ? __expf(s4[rg][r]) : 0.f;
          lsum[rg][r] += e;
          plds[w][q4 * 4 + r][c16] = f2bf_fast(e);
          plds[w][q4 * 4 + r][16 + c16] = 0;
        }
        afrag[rg] = *(const bf16x8*)(&plds[w][c16][q4 * 8]);
      }
#pragma unroll
      for (int nt = 0; nt < 3; nt++) {
        const u16* vrow = &vlds[0][nt * 16 + c16][0];
        bf16x8 bv = *(const bf16x8*)(vrow + (q4 ^ r7) * 8);
#pragma unroll
        for (int rg = 0; rg < 2; rg++)
          o[rg][nt] = __builtin_amdgcn_mfma_f32_16x16x32_bf16(afrag[rg], bv, o[rg][nt], 0, 0, 0);
      }
    }

    int b = bh >> 3, h = bh & 7;
#pragma unroll
    for (int rg = 0; rg < 2; rg++) {
      float inv[4];
#pragma unroll
      for (int r = 0; r < 4; r++) {
        float l = lsum[rg][r];
        l += __shfl_xor(l, 1);
        l += __shfl_xor(l, 2);
        l += __shfl_xor(l, 4);
        l += __shfl_xor(l, 8);
        inv[r] = 1.0f / l;
      }
#pragma unroll
      for (int nt = 0; nt < 3; nt++)
#pragma unroll
        for (int r = 0; r < 4; r++) {
          int n = n0 + rg * 16 + q4 * 4 + r;
          if (n < NTOK) outb[((size_t)(b * NTOK + n)) * 384 + h * 48 + nt * 16 + c16] = f2bf(o[rg][nt][r] * inv[r]);
        }
    }
    __syncthreads();  // protect LDS before next unit's stage(0,0)
  }
}

extern "C" void kernel_launch(void* const* d_in, const int* in_sizes, int n_in,
                              void* d_out, int out_size, void* d_ws, size_t ws_size,
                              hipStream_t stream) {
  const float* x = (const float*)d_in[0];
  const float* q_w = (const float*)d_in[1];
  const float* kv_w = (const float*)d_in[2];
  const float* proj_w = (const float*)d_in[3];
  const float* proj_b = (const float*)d_in[4];
  const float* sr_w = (const float*)d_in[5];
  const float* sr_b = (const float*)d_in[6];
  const float* ln_g = (const float*)d_in[7];
  const float* ln_b = (const float*)d_in[8];
  float* out = (float*)d_out;

  u16* ws = (u16*)d_ws;
  u16* x_b = ws;                          // 16512*384       = 6,340,608
  u16* qw_b = x_b + (size_t)ROWS_X * 384; // 147,456
  u16* kvw_b = qw_b + 147456;             // 294,912
  u16* pw_b = kvw_b + 294912;             // 147,456
  u16* q_b = pw_b + 147456;               // 32*4224*64      = 8,650,752
  u16* xln_b = q_b + (size_t)32 * NPAD_Q * 64;  // 4*544*384 = 835,584
  u16* k_b = xln_b + (size_t)4 * MPAD * 384;    // 32*640*64 = 1,310,720
  u16* vt_b = k_b + (size_t)32 * KPAD * 64;     // 32*48*640 = 983,040
  u16* attn_b = x_b;  // alias: x_b dead after q-proj GEMM

  pre_kernel<<<SRLN_BLOCKS + 2240, 384, 0, stream>>>(x, q_w, kv_w, proj_w, sr_w, sr_b,
                                                     ln_g, ln_b, x_b, qw_b, kvw_b, pw_b, xln_b);
  gemm_qkv<<<489, 256, 0, stream>>>(x_b, qw_b, xln_b, kvw_b, q_b, k_b, vt_b);
  attn_kernel<<<1024, 256, 0, stream>>>(q_b, k_b, vt_b, attn_b);
  gemm_out<<<dim3(129, 3), 256, 0, stream>>>(attn_b, pw_b, out, proj_b);
}